// Round 4
// baseline (253.371 us; speedup 1.0000x reference)
//
#include <hip/hip_runtime.h>
#include <math.h>

#define N 8192
#define D 128
#define NC 256
#define NT 64                    // 128-wide tiles per dim
#define NBLK (NT * (NT + 1) / 2) // 2080
#define KC 32                    // k-chunk depth
#define LDS_STRIDE 140           // 128 floats + 4-gap every 32 (phys map)

// phys(c) = c + 4*(c>>5): keeps float4 groups contiguous, breaks stride-32B
// bank aliasing down to 2-way (free).
__device__ __forceinline__ int physc(int c) { return c + 4 * (c >> 5); }

// ---------------------------------------------------------------------------
// Kernel 1: init packed best arrays + histogram bins
// ---------------------------------------------------------------------------
__global__ void init_kernel(unsigned long long* __restrict__ pos_pack,
                            unsigned long long* __restrict__ neg_pack,
                            int* __restrict__ hist) {
    const int t = blockIdx.x * 256 + threadIdx.x;
    if (t < N) { pos_pack[t] = 0ULL; neg_pack[t] = ~0ULL; }
    if (t < NC) hist[t] = 0;
}

// ---------------------------------------------------------------------------
// Kernel 2: normalize 64 rows/block via LDS transpose; coalesced xnT writes.
// ---------------------------------------------------------------------------
__global__ __launch_bounds__(256) void normalize_kernel(
    const float* __restrict__ x, float* __restrict__ xnT,
    float* __restrict__ sq) {
    __shared__ float Xs[64 * 129];   // pad 129: phase-3 reads 2-way clean
    __shared__ float norms[64];
    const int t = threadIdx.x;
    const int r0 = blockIdx.x * 64;

    // phase 1: load 64x128 block (coalesced float4), scalar LDS stores
#pragma unroll
    for (int p = 0; p < 8; ++p) {
        const int lin = p * 256 + t;
        const int row = lin >> 5;
        const int c0 = (lin & 31) << 2;
        const float4 v = *(const float4*)(x + (size_t)(r0 + row) * D + c0);
        float* dst = &Xs[row * 129 + c0];
        dst[0] = v.x; dst[1] = v.y; dst[2] = v.z; dst[3] = v.w;
    }
    __syncthreads();

    // phase 2: 4 threads per row compute norm, then sum of normalized squares
    {
        const int r = t >> 2, q = t & 3;
        const float* src = &Xs[r * 129 + q * 32];
        float s = 0.f;
#pragma unroll
        for (int i = 0; i < 32; ++i) s = fmaf(src[i], src[i], s);
        s += __shfl_xor(s, 1, 64);
        s += __shfl_xor(s, 2, 64);
        const float nrm = sqrtf(s);
        float t2 = 0.f;
#pragma unroll
        for (int i = 0; i < 32; ++i) {
            const float n = src[i] / nrm;
            t2 = fmaf(n, n, t2);
        }
        t2 += __shfl_xor(t2, 1, 64);
        t2 += __shfl_xor(t2, 2, 64);
        if (q == 0) { sq[r0 + r] = t2; norms[r] = nrm; }
    }
    __syncthreads();

    // phase 3: transposed write; lane=row -> 256 B contiguous stores per k
    {
        const int r_off = t & 63;
        const int w = t >> 6;
        const float nrm = norms[r_off];
#pragma unroll
        for (int m = 0; m < 32; ++m) {
            const int k = w * 32 + m;
            xnT[(size_t)k * N + r0 + r_off] = Xs[r_off * 129 + k] / nrm;
        }
    }
}

// ---------------------------------------------------------------------------
// Kernel 3: label histogram
// ---------------------------------------------------------------------------
__global__ void hist_kernel(const int* __restrict__ labels, int* __restrict__ hist) {
    __shared__ int h[NC];
    h[threadIdx.x] = 0;
    __syncthreads();
    const int base = blockIdx.x * 1024;
#pragma unroll
    for (int s = 0; s < 4; ++s) atomicAdd(&h[labels[base + s * 256 + threadIdx.x]], 1);
    __syncthreads();
    atomicAdd(&hist[threadIdx.x], h[threadIdx.x]);
}

// ---------------------------------------------------------------------------
// Kernel 4: symmetric 128x128-tile Gram + fused arg-reductions, 8x8/thread.
// ---------------------------------------------------------------------------
__device__ __forceinline__ unsigned int fbits(float f) {
    union { float f; unsigned int u; } x; x.f = f; return x.u;
}
__device__ __forceinline__ unsigned long long pack_pos(float v, int j) {
    return ((unsigned long long)fbits(v) << 32) | (unsigned int)(8191 - j);
}
__device__ __forceinline__ unsigned long long pack_neg(float v, int j) {
    return ((unsigned long long)fbits(v) << 32) | (unsigned int)j;
}
__device__ __forceinline__ void red_max(float& v, int& j, int mask) {
    const float ov = __shfl_xor(v, mask, 64);
    const int   oj = __shfl_xor(j, mask, 64);
    if (ov > v || (ov == v && oj < j)) { v = ov; j = oj; }
}
__device__ __forceinline__ void red_min(float& v, int& j, int mask) {
    const float ov = __shfl_xor(v, mask, 64);
    const int   oj = __shfl_xor(j, mask, 64);
    if (ov < v || (ov == v && oj < j)) { v = ov; j = oj; }
}

__global__ __launch_bounds__(256, 4) void miner_kernel(
    const float* __restrict__ xnT, const float* __restrict__ sq,
    const int* __restrict__ labels,
    unsigned long long* __restrict__ pos_pack,
    unsigned long long* __restrict__ neg_pack) {
    __shared__ float As[KC * LDS_STRIDE];  // 17.5 KB; reused as u64 scratch
    __shared__ float Bs[KC * LDS_STRIDE];  // 17.5 KB
    __shared__ float sqI[128], sqJ[128];
    __shared__ int   lbI[128], lbJ[128];

    const int t  = threadIdx.x;
    const int tx = t & 15;     // 8 cols: 8*tx..8*tx+7
    const int ty = t >> 4;     // 8 rows: 8*ty..8*ty+7

    // decode upper-triangular (bi, bj), bi <= bj, NT=64
    const int b = blockIdx.x;
    int bi = (int)((129.0f - sqrtf(16641.0f - 8.0f * (float)b)) * 0.5f);
    while (bi > 0 && (bi * NT - bi * (bi - 1) / 2) > b) --bi;
    while (((bi + 1) * NT - (bi + 1) * bi / 2) <= b) ++bi;
    const int bj = bi + (b - (bi * NT - bi * (bi - 1) / 2));
    const int I0 = bi * 128, J0 = bj * 128;
    const bool diag = (bi == bj);

    if (t < 128) { sqI[t] = sq[I0 + t]; lbI[t] = labels[I0 + t]; }
    else         { sqJ[t - 128] = sq[J0 + t - 128]; lbJ[t - 128] = labels[J0 + t - 128]; }

    const int pA = 8 * ty + 4 * (ty >> 2);
    const int pB = 8 * tx + 4 * (tx >> 2);

    float acc[8][8] = {};
    for (int kc = 0; kc < D; kc += KC) {
        __syncthreads();
#pragma unroll
        for (int p = 0; p < 4; ++p) {
            const int lin = p * 256 + t;
            const int k = lin >> 5;
            const int c0 = (lin & 31) << 2;
            const int ph = physc(c0);
            *(float4*)&As[k * LDS_STRIDE + ph] =
                *(const float4*)(xnT + (size_t)(kc + k) * N + I0 + c0);
            *(float4*)&Bs[k * LDS_STRIDE + ph] =
                *(const float4*)(xnT + (size_t)(kc + k) * N + J0 + c0);
        }
        __syncthreads();
#pragma unroll 8
        for (int k = 0; k < KC; ++k) {
            const float4 a0 = *(const float4*)&As[k * LDS_STRIDE + pA];
            const float4 a1 = *(const float4*)&As[k * LDS_STRIDE + pA + 4];
            const float4 b0 = *(const float4*)&Bs[k * LDS_STRIDE + pB];
            const float4 b1 = *(const float4*)&Bs[k * LDS_STRIDE + pB + 4];
            const float a[8] = {a0.x, a0.y, a0.z, a0.w, a1.x, a1.y, a1.z, a1.w};
            const float bb[8] = {b0.x, b0.y, b0.z, b0.w, b1.x, b1.y, b1.z, b1.w};
#pragma unroll
            for (int ri = 0; ri < 8; ++ri)
#pragma unroll
                for (int ci = 0; ci < 8; ++ci)
                    acc[ri][ci] = fmaf(a[ri], bb[ci], acc[ri][ci]);
        }
    }

    // ---- epilogue: d2 in place ----
    int li[8], lj[8];
#pragma unroll
    for (int ri = 0; ri < 8; ++ri) li[ri] = lbI[8 * ty + ri];
#pragma unroll
    for (int ci = 0; ci < 8; ++ci) lj[ci] = lbJ[8 * tx + ci];
#pragma unroll
    for (int ri = 0; ri < 8; ++ri) {
        const float si = sqI[8 * ty + ri];
#pragma unroll
        for (int ci = 0; ci < 8; ++ci)
            acc[ri][ci] = fmaxf(si + sqJ[8 * tx + ci] - 2.0f * acc[ri][ci], 0.0f);
    }

    // I-side: per-row best over 8 cols, reduce across tx (masks 1..8), commit
    {
        float bpv[8], bnv[8]; int bpj[8], bnj[8];
#pragma unroll
        for (int ri = 0; ri < 8; ++ri) {
            bpv[ri] = -1.0f; bpj[ri] = 0; bnv[ri] = INFINITY; bnj[ri] = 0;
            const int row = I0 + 8 * ty + ri;
#pragma unroll
            for (int ci = 0; ci < 8; ++ci) {
                const int col = J0 + 8 * tx + ci;
                const bool same = (li[ri] == lj[ci]);
                const float vp = (same && row != col) ? acc[ri][ci] : 0.0f;
                if (vp > bpv[ri]) { bpv[ri] = vp; bpj[ri] = col; }
                const float vn = same ? INFINITY : acc[ri][ci];
                if (vn < bnv[ri]) { bnv[ri] = vn; bnj[ri] = col; }
            }
        }
#pragma unroll
        for (int m = 1; m < 16; m <<= 1)
#pragma unroll
            for (int ri = 0; ri < 8; ++ri) {
                red_max(bpv[ri], bpj[ri], m);
                red_min(bnv[ri], bnj[ri], m);
            }
        if (tx == 0) {
#pragma unroll
            for (int ri = 0; ri < 8; ++ri) {
                atomicMax(&pos_pack[I0 + 8 * ty + ri], pack_pos(bpv[ri], bpj[ri]));
                atomicMin(&neg_pack[I0 + 8 * ty + ri], pack_neg(bnv[ri], bnj[ri]));
            }
        }
    }

    // J-side (skip on diagonal): per-col best over 8 rows, reduce across ty
    // within wave (masks 16,32), then cross-wave via LDS, commit once per col.
    if (!diag) {
        float bpv[8], bnv[8]; int bpj[8], bnj[8];
#pragma unroll
        for (int ci = 0; ci < 8; ++ci) {
            bpv[ci] = -1.0f; bpj[ci] = 0; bnv[ci] = INFINITY; bnj[ci] = 0;
#pragma unroll
            for (int ri = 0; ri < 8; ++ri) {
                const int row = I0 + 8 * ty + ri;
                const bool same = (li[ri] == lj[ci]);   // no self off-diagonal
                const float vp = same ? acc[ri][ci] : 0.0f;
                if (vp > bpv[ci]) { bpv[ci] = vp; bpj[ci] = row; }
                const float vn = same ? INFINITY : acc[ri][ci];
                if (vn < bnv[ci]) { bnv[ci] = vn; bnj[ci] = row; }
            }
        }
#pragma unroll
        for (int m = 16; m < 64; m <<= 1)
#pragma unroll
            for (int ci = 0; ci < 8; ++ci) {
                red_max(bpv[ci], bpj[ci], m);
                red_min(bnv[ci], bnj[ci], m);
            }
        unsigned long long* scr = (unsigned long long*)As;  // 1024 u64 = 8 KB
        __syncthreads();
        const int w = t >> 6;
        if ((t & 48) == 0) {
#pragma unroll
            for (int ci = 0; ci < 8; ++ci) {
                scr[w * 128 + 8 * tx + ci]       = pack_pos(bpv[ci], bpj[ci]);
                scr[512 + w * 128 + 8 * tx + ci] = pack_neg(bnv[ci], bnj[ci]);
            }
        }
        __syncthreads();
        if (t < 128) {
            unsigned long long mp = 0ULL, mn = ~0ULL;
#pragma unroll
            for (int ww = 0; ww < 4; ++ww) {
                const unsigned long long p = scr[ww * 128 + t];
                const unsigned long long q = scr[512 + ww * 128 + t];
                if (p > mp) mp = p;
                if (q < mn) mn = q;
            }
            atomicMax(&pos_pack[J0 + t], mp);
            atomicMin(&neg_pack[J0 + t], mn);
        }
    }
}

// ---------------------------------------------------------------------------
// Kernel 5: finalize -> int32 outputs [anchor | pos | neg | keep]
// ---------------------------------------------------------------------------
__global__ void finalize_kernel(const unsigned long long* __restrict__ pos_pack,
                                const unsigned long long* __restrict__ neg_pack,
                                const int* __restrict__ labels,
                                const int* __restrict__ hist,
                                int* __restrict__ out) {
    const int r = blockIdx.x * 256 + threadIdx.x;
    out[r]         = r;
    out[N + r]     = 8191 - (int)(pos_pack[r] & 0xFFFFFFFFULL);
    out[2 * N + r] = (int)(neg_pack[r] & 0xFFFFFFFFULL);
    const int cnt = hist[labels[r]];
    out[3 * N + r] = (cnt >= 2 && cnt < N) ? 1 : 0;
}

extern "C" void kernel_launch(void* const* d_in, const int* in_sizes, int n_in,
                              void* d_out, int out_size, void* d_ws, size_t ws_size,
                              hipStream_t stream) {
    const float* x      = (const float*)d_in[0];
    const int*   labels = (const int*)d_in[1];
    int* out = (int*)d_out;

    float* ws  = (float*)d_ws;
    float* xnT = ws;                                        // N*D floats (4 MB)
    float* sq  = xnT + (size_t)N * D;                       // N floats
    unsigned long long* pos_pack =
        (unsigned long long*)(sq + N);                      // N u64
    unsigned long long* neg_pack = pos_pack + N;            // N u64
    int* hist = (int*)(neg_pack + N);                       // NC ints

    init_kernel<<<N / 256, 256, 0, stream>>>(pos_pack, neg_pack, hist);
    normalize_kernel<<<N / 64, 256, 0, stream>>>(x, xnT, sq);
    hist_kernel<<<N / 1024, 256, 0, stream>>>(labels, hist);
    miner_kernel<<<NBLK, 256, 0, stream>>>(xnT, sq, labels, pos_pack, neg_pack);
    finalize_kernel<<<N / 256, 256, 0, stream>>>(pos_pack, neg_pack, labels, hist, out);
}

// Round 5
// 246.421 us; speedup vs baseline: 1.0282x; 1.0282x over previous
//
#include <hip/hip_runtime.h>
#include <math.h>

#define N 8192
#define D 128
#define NC 256
#define NT 64                    // 128-wide tiles per dim
#define NBLK (NT * (NT + 1) / 2) // 2080
#define KC 32                    // k-chunk depth
#define LDSW 132                 // 128 + 4 pad

// ---------------------------------------------------------------------------
// Kernel 1: normalize 64 rows/block via LDS transpose; coalesced xnT writes;
// also accumulates the label histogram (hist pre-zeroed by hipMemsetAsync).
// ---------------------------------------------------------------------------
__global__ __launch_bounds__(256) void normalize_kernel(
    const float* __restrict__ x, const int* __restrict__ labels,
    float* __restrict__ xnT, float* __restrict__ sq, int* __restrict__ hist) {
    __shared__ float Xs[64 * 129];
    __shared__ float norms[64];
    const int t = threadIdx.x;
    const int r0 = blockIdx.x * 64;

    // phase 1: load 64x128 block (coalesced float4)
#pragma unroll
    for (int p = 0; p < 8; ++p) {
        const int lin = p * 256 + t;
        const int row = lin >> 5;
        const int c0 = (lin & 31) << 2;
        const float4 v = *(const float4*)(x + (size_t)(r0 + row) * D + c0);
        float* dst = &Xs[row * 129 + c0];
        dst[0] = v.x; dst[1] = v.y; dst[2] = v.z; dst[3] = v.w;
    }
    __syncthreads();

    // phase 2: 4 threads per row -> norm, then sum of normalized squares
    {
        const int r = t >> 2, q = t & 3;
        const float* src = &Xs[r * 129 + q * 32];
        float s = 0.f;
#pragma unroll
        for (int i = 0; i < 32; ++i) s = fmaf(src[i], src[i], s);
        s += __shfl_xor(s, 1, 64);
        s += __shfl_xor(s, 2, 64);
        const float nrm = sqrtf(s);
        float t2 = 0.f;
#pragma unroll
        for (int i = 0; i < 32; ++i) {
            const float n = src[i] / nrm;
            t2 = fmaf(n, n, t2);
        }
        t2 += __shfl_xor(t2, 1, 64);
        t2 += __shfl_xor(t2, 2, 64);
        if (q == 0) { sq[r0 + r] = t2; norms[r] = nrm; }
    }
    __syncthreads();

    // phase 3: transposed write; lane=row -> 256 B contiguous per k
    {
        const int r_off = t & 63;
        const int w = t >> 6;
        const float nrm = norms[r_off];
#pragma unroll
        for (int m = 0; m < 32; ++m) {
            const int k = w * 32 + m;
            xnT[(size_t)k * N + r0 + r_off] = Xs[r_off * 129 + k] / nrm;
        }
    }

    // histogram of this block's 64 labels
    if (t < 64) atomicAdd(&hist[labels[r0 + t]], 1);
}

// ---------------------------------------------------------------------------
// Kernel 2: symmetric 128x128-tile Gram + fused arg-reductions, 8x8/thread.
// Fragments split 4+4 (cols {4tx..+3, 64+4tx..+3}): B-reads 2-way aliased
// (free), A-reads broadcast, staging writes consecutive. waves_per_eu pinned
// to (4,4): 128-VGPR budget, no spill (round-4 lesson: min-only bound let the
// allocator squeeze to 64 VGPRs and spill 250 MB to scratch).
// ---------------------------------------------------------------------------
__device__ __forceinline__ unsigned int fbits(float f) {
    union { float f; unsigned int u; } x; x.f = f; return x.u;
}
__device__ __forceinline__ unsigned long long pack_pos(float v, int j) {
    return ((unsigned long long)fbits(v) << 32) | (unsigned int)(8191 - j);
}
__device__ __forceinline__ unsigned long long pack_neg(float v, int j) {
    return ((unsigned long long)fbits(v) << 32) | (unsigned int)j;
}
__device__ __forceinline__ void red_max(float& v, int& j, int mask) {
    const float ov = __shfl_xor(v, mask, 64);
    const int   oj = __shfl_xor(j, mask, 64);
    if (ov > v || (ov == v && oj < j)) { v = ov; j = oj; }
}
__device__ __forceinline__ void red_min(float& v, int& j, int mask) {
    const float ov = __shfl_xor(v, mask, 64);
    const int   oj = __shfl_xor(j, mask, 64);
    if (ov < v || (ov == v && oj < j)) { v = ov; j = oj; }
}

__global__ __launch_bounds__(256)
__attribute__((amdgpu_waves_per_eu(4, 4)))
void miner_kernel(
    const float* __restrict__ xnT, const float* __restrict__ sq,
    const int* __restrict__ labels,
    unsigned long long* __restrict__ pos_pack,
    unsigned long long* __restrict__ neg_pack) {
    __shared__ float As[KC * LDSW];   // 16.5 KB; reused as u64 scratch later
    __shared__ float Bs[KC * LDSW];   // 16.5 KB
    __shared__ float sqI[128], sqJ[128];
    __shared__ int   lbI[128], lbJ[128];

    const int t  = threadIdx.x;
    const int tx = t & 15;
    const int ty = t >> 4;

    // decode upper-triangular (bi, bj), bi <= bj, NT=64
    const int b = blockIdx.x;
    int bi = (int)((129.0f - sqrtf(16641.0f - 8.0f * (float)b)) * 0.5f);
    while (bi > 0 && (bi * NT - bi * (bi - 1) / 2) > b) --bi;
    while (((bi + 1) * NT - (bi + 1) * bi / 2) <= b) ++bi;
    const int bj = bi + (b - (bi * NT - bi * (bi - 1) / 2));
    const int I0 = bi * 128, J0 = bj * 128;
    const bool diag = (bi == bj);

    if (t < 128) { sqI[t] = sq[I0 + t]; lbI[t] = labels[I0 + t]; }
    else         { sqJ[t - 128] = sq[J0 + t - 128]; lbJ[t - 128] = labels[J0 + t - 128]; }

    const int cA = 4 * ty;   // rows 4ty..+3 and 64+4ty..+3
    const int cB = 4 * tx;   // cols 4tx..+3 and 64+4tx..+3

    float acc[8][8] = {};
    for (int kc = 0; kc < D; kc += KC) {
        __syncthreads();
#pragma unroll
        for (int p = 0; p < 4; ++p) {
            const int lin = p * 256 + t;
            const int k = lin >> 5;
            const int c0 = (lin & 31) << 2;
            *(float4*)&As[k * LDSW + c0] =
                *(const float4*)(xnT + (size_t)(kc + k) * N + I0 + c0);
            *(float4*)&Bs[k * LDSW + c0] =
                *(const float4*)(xnT + (size_t)(kc + k) * N + J0 + c0);
        }
        __syncthreads();
#pragma unroll 8
        for (int k = 0; k < KC; ++k) {
            const float4 a0 = *(const float4*)&As[k * LDSW + cA];
            const float4 a1 = *(const float4*)&As[k * LDSW + 64 + cA];
            const float4 b0 = *(const float4*)&Bs[k * LDSW + cB];
            const float4 b1 = *(const float4*)&Bs[k * LDSW + 64 + cB];
            const float a[8]  = {a0.x, a0.y, a0.z, a0.w, a1.x, a1.y, a1.z, a1.w};
            const float bb[8] = {b0.x, b0.y, b0.z, b0.w, b1.x, b1.y, b1.z, b1.w};
#pragma unroll
            for (int ri = 0; ri < 8; ++ri)
#pragma unroll
                for (int ci = 0; ci < 8; ++ci)
                    acc[ri][ci] = fmaf(a[ri], bb[ci], acc[ri][ci]);
        }
    }

    // local row/col offsets of this thread's fragment
    int lrow[8], lcol[8];
#pragma unroll
    for (int i = 0; i < 8; ++i) {
        lrow[i] = 4 * ty + (i & 3) + 64 * (i >> 2);
        lcol[i] = 4 * tx + (i & 3) + 64 * (i >> 2);
    }
    int li[8], lj[8];
#pragma unroll
    for (int i = 0; i < 8; ++i) { li[i] = lbI[lrow[i]]; lj[i] = lbJ[lcol[i]]; }

    // d2 in place
#pragma unroll
    for (int ri = 0; ri < 8; ++ri) {
        const float si = sqI[lrow[ri]];
#pragma unroll
        for (int ci = 0; ci < 8; ++ci)
            acc[ri][ci] = fmaxf(si + sqJ[lcol[ci]] - 2.0f * acc[ri][ci], 0.0f);
    }

    // I-side: per-row best over this thread's 8 cols (ascending j), reduce
    // across tx (masks 1..8, index tie-break), commit.
    {
        float bpv[8], bnv[8]; int bpj[8], bnj[8];
#pragma unroll
        for (int ri = 0; ri < 8; ++ri) {
            bpv[ri] = -1.0f; bpj[ri] = 0; bnv[ri] = INFINITY; bnj[ri] = 0;
            const int row = I0 + lrow[ri];
#pragma unroll
            for (int ci = 0; ci < 8; ++ci) {
                const int col = J0 + lcol[ci];
                const bool same = (li[ri] == lj[ci]);
                const float vp = (same && row != col) ? acc[ri][ci] : 0.0f;
                if (vp > bpv[ri]) { bpv[ri] = vp; bpj[ri] = col; }
                const float vn = same ? INFINITY : acc[ri][ci];
                if (vn < bnv[ri]) { bnv[ri] = vn; bnj[ri] = col; }
            }
        }
#pragma unroll
        for (int m = 1; m < 16; m <<= 1)
#pragma unroll
            for (int ri = 0; ri < 8; ++ri) {
                red_max(bpv[ri], bpj[ri], m);
                red_min(bnv[ri], bnj[ri], m);
            }
        if (tx == 0) {
#pragma unroll
            for (int ri = 0; ri < 8; ++ri) {
                atomicMax(&pos_pack[I0 + lrow[ri]], pack_pos(bpv[ri], bpj[ri]));
                atomicMin(&neg_pack[I0 + lrow[ri]], pack_neg(bnv[ri], bnj[ri]));
            }
        }
    }

    // J-side (skip on diagonal): per-col best over 8 rows (ascending), reduce
    // across in-wave ty (masks 16,32), cross-wave merge via LDS, one commit/col.
    if (!diag) {
        float bpv[8], bnv[8]; int bpj[8], bnj[8];
#pragma unroll
        for (int ci = 0; ci < 8; ++ci) {
            bpv[ci] = -1.0f; bpj[ci] = 0; bnv[ci] = INFINITY; bnj[ci] = 0;
#pragma unroll
            for (int ri = 0; ri < 8; ++ri) {
                const int row = I0 + lrow[ri];
                const bool same = (li[ri] == lj[ci]);   // no self off-diagonal
                const float vp = same ? acc[ri][ci] : 0.0f;
                if (vp > bpv[ci]) { bpv[ci] = vp; bpj[ci] = row; }
                const float vn = same ? INFINITY : acc[ri][ci];
                if (vn < bnv[ci]) { bnv[ci] = vn; bnj[ci] = row; }
            }
        }
#pragma unroll
        for (int m = 16; m < 64; m <<= 1)
#pragma unroll
            for (int ci = 0; ci < 8; ++ci) {
                red_max(bpv[ci], bpj[ci], m);
                red_min(bnv[ci], bnj[ci], m);
            }
        unsigned long long* scr = (unsigned long long*)As;  // 1024 u64 = 8 KB
        __syncthreads();
        const int w = t >> 6;
        if ((t & 48) == 0) {
#pragma unroll
            for (int ci = 0; ci < 8; ++ci) {
                scr[w * 128 + lcol[ci]]       = pack_pos(bpv[ci], bpj[ci]);
                scr[512 + w * 128 + lcol[ci]] = pack_neg(bnv[ci], bnj[ci]);
            }
        }
        __syncthreads();
        if (t < 128) {
            unsigned long long mp = 0ULL, mn = ~0ULL;
#pragma unroll
            for (int ww = 0; ww < 4; ++ww) {
                const unsigned long long p = scr[ww * 128 + t];
                const unsigned long long q = scr[512 + ww * 128 + t];
                if (p > mp) mp = p;
                if (q < mn) mn = q;
            }
            atomicMax(&pos_pack[J0 + t], mp);
            atomicMin(&neg_pack[J0 + t], mn);
        }
    }
}

// ---------------------------------------------------------------------------
// Kernel 3: finalize -> int32 outputs [anchor | pos | neg | keep]
// ---------------------------------------------------------------------------
__global__ void finalize_kernel(const unsigned long long* __restrict__ pos_pack,
                                const unsigned long long* __restrict__ neg_pack,
                                const int* __restrict__ labels,
                                const int* __restrict__ hist,
                                int* __restrict__ out) {
    const int r = blockIdx.x * 256 + threadIdx.x;
    out[r]         = r;
    out[N + r]     = 8191 - (int)(pos_pack[r] & 0xFFFFFFFFULL);
    out[2 * N + r] = (int)(neg_pack[r] & 0xFFFFFFFFULL);
    const int cnt = hist[labels[r]];
    out[3 * N + r] = (cnt >= 2 && cnt < N) ? 1 : 0;
}

extern "C" void kernel_launch(void* const* d_in, const int* in_sizes, int n_in,
                              void* d_out, int out_size, void* d_ws, size_t ws_size,
                              hipStream_t stream) {
    const float* x      = (const float*)d_in[0];
    const int*   labels = (const int*)d_in[1];
    int* out = (int*)d_out;

    float* ws  = (float*)d_ws;
    float* xnT = ws;                                        // N*D floats (4 MB)
    float* sq  = xnT + (size_t)N * D;                       // N floats
    unsigned long long* pos_pack =
        (unsigned long long*)(sq + N);                      // N u64
    int* hist = (int*)(pos_pack + N);                       // NC ints (adjacent: one memset)
    unsigned long long* neg_pack =
        (unsigned long long*)(hist + NC);                   // N u64

    hipMemsetAsync(pos_pack, 0x00, N * 8 + NC * 4, stream);     // pos init + hist zero
    hipMemsetAsync(neg_pack, 0xFF, N * 8, stream);              // neg init
    normalize_kernel<<<N / 64, 256, 0, stream>>>(x, labels, xnT, sq, hist);
    miner_kernel<<<NBLK, 256, 0, stream>>>(xnT, sq, labels, pos_pack, neg_pack);
    finalize_kernel<<<N / 256, 256, 0, stream>>>(pos_pack, neg_pack, labels, hist, out);
}

// Round 6
// 227.554 us; speedup vs baseline: 1.1135x; 1.0829x over previous
//
#include <hip/hip_runtime.h>
#include <math.h>

#define N 8192
#define D 128
#define NC 256
#define NT 64                    // 128-wide tiles per dim
#define NBLK (NT * (NT + 1) / 2) // 2080
#define KC 32                    // k-chunk depth
#define LDSW 132                 // 128 + 4 pad

// ---------------------------------------------------------------------------
// Kernel 1: normalize 64 rows/block via LDS transpose; coalesced xnT writes;
// also accumulates the label histogram (hist pre-zeroed by hipMemsetAsync).
// ---------------------------------------------------------------------------
__global__ __launch_bounds__(256) void normalize_kernel(
    const float* __restrict__ x, const int* __restrict__ labels,
    float* __restrict__ xnT, float* __restrict__ sq, int* __restrict__ hist) {
    __shared__ float Xs[64 * 129];
    __shared__ float norms[64];
    const int t = threadIdx.x;
    const int r0 = blockIdx.x * 64;

    // phase 1: load 64x128 block (coalesced float4)
#pragma unroll
    for (int p = 0; p < 8; ++p) {
        const int lin = p * 256 + t;
        const int row = lin >> 5;
        const int c0 = (lin & 31) << 2;
        const float4 v = *(const float4*)(x + (size_t)(r0 + row) * D + c0);
        float* dst = &Xs[row * 129 + c0];
        dst[0] = v.x; dst[1] = v.y; dst[2] = v.z; dst[3] = v.w;
    }
    __syncthreads();

    // phase 2: 4 threads per row -> norm, then sum of normalized squares
    {
        const int r = t >> 2, q = t & 3;
        const float* src = &Xs[r * 129 + q * 32];
        float s = 0.f;
#pragma unroll
        for (int i = 0; i < 32; ++i) s = fmaf(src[i], src[i], s);
        s += __shfl_xor(s, 1, 64);
        s += __shfl_xor(s, 2, 64);
        const float nrm = sqrtf(s);
        float t2 = 0.f;
#pragma unroll
        for (int i = 0; i < 32; ++i) {
            const float n = src[i] / nrm;
            t2 = fmaf(n, n, t2);
        }
        t2 += __shfl_xor(t2, 1, 64);
        t2 += __shfl_xor(t2, 2, 64);
        if (q == 0) { sq[r0 + r] = t2; norms[r] = nrm; }
    }
    __syncthreads();

    // phase 3: transposed write; lane=row -> 256 B contiguous per k
    {
        const int r_off = t & 63;
        const int w = t >> 6;
        const float nrm = norms[r_off];
#pragma unroll
        for (int m = 0; m < 32; ++m) {
            const int k = w * 32 + m;
            xnT[(size_t)k * N + r0 + r_off] = Xs[r_off * 129 + k] / nrm;
        }
    }

    // histogram of this block's 64 labels
    if (t < 64) atomicAdd(&hist[labels[r0 + t]], 1);
}

// ---------------------------------------------------------------------------
// Kernel 2: symmetric 128x128-tile Gram + fused arg-reductions, 8x8/thread.
// NO occupancy hints: every hinted variant (launch_bounds(256,4) in R4,
// waves_per_eu(4,4) in R5) pinned the VGPR budget to 64 and spilled ~300 MB
// to scratch (FETCH/WRITE blowup). Plain launch_bounds(256) is the only
// configuration observed to grant >64 VGPRs (R1: 92). k-loop unroll kept at
// 4 to bound the scheduler's in-flight operand window.
// ---------------------------------------------------------------------------
__device__ __forceinline__ unsigned int fbits(float f) {
    union { float f; unsigned int u; } x; x.f = f; return x.u;
}
__device__ __forceinline__ unsigned long long pack_pos(float v, int j) {
    return ((unsigned long long)fbits(v) << 32) | (unsigned int)(8191 - j);
}
__device__ __forceinline__ unsigned long long pack_neg(float v, int j) {
    return ((unsigned long long)fbits(v) << 32) | (unsigned int)j;
}
__device__ __forceinline__ void red_max(float& v, int& j, int mask) {
    const float ov = __shfl_xor(v, mask, 64);
    const int   oj = __shfl_xor(j, mask, 64);
    if (ov > v || (ov == v && oj < j)) { v = ov; j = oj; }
}
__device__ __forceinline__ void red_min(float& v, int& j, int mask) {
    const float ov = __shfl_xor(v, mask, 64);
    const int   oj = __shfl_xor(j, mask, 64);
    if (ov < v || (ov == v && oj < j)) { v = ov; j = oj; }
}

__global__ __launch_bounds__(256) void miner_kernel(
    const float* __restrict__ xnT, const float* __restrict__ sq,
    const int* __restrict__ labels,
    unsigned long long* __restrict__ pos_pack,
    unsigned long long* __restrict__ neg_pack) {
    __shared__ float As[KC * LDSW];   // 16.5 KB; reused as u64 scratch later
    __shared__ float Bs[KC * LDSW];   // 16.5 KB
    __shared__ float sqI[128], sqJ[128];
    __shared__ int   lbI[128], lbJ[128];

    const int t  = threadIdx.x;
    const int tx = t & 15;
    const int ty = t >> 4;

    // decode upper-triangular (bi, bj), bi <= bj, NT=64
    const int b = blockIdx.x;
    int bi = (int)((129.0f - sqrtf(16641.0f - 8.0f * (float)b)) * 0.5f);
    while (bi > 0 && (bi * NT - bi * (bi - 1) / 2) > b) --bi;
    while (((bi + 1) * NT - (bi + 1) * bi / 2) <= b) ++bi;
    const int bj = bi + (b - (bi * NT - bi * (bi - 1) / 2));
    const int I0 = bi * 128, J0 = bj * 128;
    const bool diag = (bi == bj);

    if (t < 128) { sqI[t] = sq[I0 + t]; lbI[t] = labels[I0 + t]; }
    else         { sqJ[t - 128] = sq[J0 + t - 128]; lbJ[t - 128] = labels[J0 + t - 128]; }

    const int cA = 4 * ty;   // rows 4ty..+3 and 64+4ty..+3
    const int cB = 4 * tx;   // cols 4tx..+3 and 64+4tx..+3
    const float* gA = xnT + I0;
    const float* gB = xnT + J0;

    float acc[8][8] = {};
    for (int kc = 0; kc < D; kc += KC) {
        __syncthreads();
#pragma unroll
        for (int p = 0; p < 4; ++p) {
            const int lin = p * 256 + t;
            const int k = lin >> 5;
            const int c0 = (lin & 31) << 2;
            *(float4*)&As[k * LDSW + c0] =
                *(const float4*)(gA + (size_t)(kc + k) * N + c0);
            *(float4*)&Bs[k * LDSW + c0] =
                *(const float4*)(gB + (size_t)(kc + k) * N + c0);
        }
        __syncthreads();
#pragma unroll 4
        for (int k = 0; k < KC; ++k) {
            const float4 a0 = *(const float4*)&As[k * LDSW + cA];
            const float4 a1 = *(const float4*)&As[k * LDSW + 64 + cA];
            const float4 b0 = *(const float4*)&Bs[k * LDSW + cB];
            const float4 b1 = *(const float4*)&Bs[k * LDSW + 64 + cB];
            const float a[8]  = {a0.x, a0.y, a0.z, a0.w, a1.x, a1.y, a1.z, a1.w};
            const float bb[8] = {b0.x, b0.y, b0.z, b0.w, b1.x, b1.y, b1.z, b1.w};
#pragma unroll
            for (int ri = 0; ri < 8; ++ri)
#pragma unroll
                for (int ci = 0; ci < 8; ++ci)
                    acc[ri][ci] = fmaf(a[ri], bb[ci], acc[ri][ci]);
        }
    }

    // local row/col offsets of this thread's fragment
    int lrow[8], lcol[8];
#pragma unroll
    for (int i = 0; i < 8; ++i) {
        lrow[i] = 4 * ty + (i & 3) + 64 * (i >> 2);
        lcol[i] = 4 * tx + (i & 3) + 64 * (i >> 2);
    }
    int li[8], lj[8];
#pragma unroll
    for (int i = 0; i < 8; ++i) { li[i] = lbI[lrow[i]]; lj[i] = lbJ[lcol[i]]; }

    // d2 in place
#pragma unroll
    for (int ri = 0; ri < 8; ++ri) {
        const float si = sqI[lrow[ri]];
#pragma unroll
        for (int ci = 0; ci < 8; ++ci)
            acc[ri][ci] = fmaxf(si + sqJ[lcol[ci]] - 2.0f * acc[ri][ci], 0.0f);
    }

    // I-side: per-row best over this thread's 8 cols (ascending j), reduce
    // across tx (masks 1..8, index tie-break), commit.
    {
        float bpv[8], bnv[8]; int bpj[8], bnj[8];
#pragma unroll
        for (int ri = 0; ri < 8; ++ri) {
            bpv[ri] = -1.0f; bpj[ri] = 0; bnv[ri] = INFINITY; bnj[ri] = 0;
            const int row = I0 + lrow[ri];
#pragma unroll
            for (int ci = 0; ci < 8; ++ci) {
                const int col = J0 + lcol[ci];
                const bool same = (li[ri] == lj[ci]);
                const float vp = (same && row != col) ? acc[ri][ci] : 0.0f;
                if (vp > bpv[ri]) { bpv[ri] = vp; bpj[ri] = col; }
                const float vn = same ? INFINITY : acc[ri][ci];
                if (vn < bnv[ri]) { bnv[ri] = vn; bnj[ri] = col; }
            }
        }
#pragma unroll
        for (int m = 1; m < 16; m <<= 1)
#pragma unroll
            for (int ri = 0; ri < 8; ++ri) {
                red_max(bpv[ri], bpj[ri], m);
                red_min(bnv[ri], bnj[ri], m);
            }
        if (tx == 0) {
#pragma unroll
            for (int ri = 0; ri < 8; ++ri) {
                atomicMax(&pos_pack[I0 + lrow[ri]], pack_pos(bpv[ri], bpj[ri]));
                atomicMin(&neg_pack[I0 + lrow[ri]], pack_neg(bnv[ri], bnj[ri]));
            }
        }
    }

    // J-side (skip on diagonal): per-col best over 8 rows (ascending), reduce
    // across in-wave ty (masks 16,32), cross-wave merge via LDS, one commit/col.
    if (!diag) {
        float bpv[8], bnv[8]; int bpj[8], bnj[8];
#pragma unroll
        for (int ci = 0; ci < 8; ++ci) {
            bpv[ci] = -1.0f; bpj[ci] = 0; bnv[ci] = INFINITY; bnj[ci] = 0;
#pragma unroll
            for (int ri = 0; ri < 8; ++ri) {
                const int row = I0 + lrow[ri];
                const bool same = (li[ri] == lj[ci]);   // no self off-diagonal
                const float vp = same ? acc[ri][ci] : 0.0f;
                if (vp > bpv[ci]) { bpv[ci] = vp; bpj[ci] = row; }
                const float vn = same ? INFINITY : acc[ri][ci];
                if (vn < bnv[ci]) { bnv[ci] = vn; bnj[ci] = row; }
            }
        }
#pragma unroll
        for (int m = 16; m < 64; m <<= 1)
#pragma unroll
            for (int ci = 0; ci < 8; ++ci) {
                red_max(bpv[ci], bpj[ci], m);
                red_min(bnv[ci], bnj[ci], m);
            }
        unsigned long long* scr = (unsigned long long*)As;  // 1024 u64 = 8 KB
        __syncthreads();
        const int w = t >> 6;
        if ((t & 48) == 0) {
#pragma unroll
            for (int ci = 0; ci < 8; ++ci) {
                scr[w * 128 + lcol[ci]]       = pack_pos(bpv[ci], bpj[ci]);
                scr[512 + w * 128 + lcol[ci]] = pack_neg(bnv[ci], bnj[ci]);
            }
        }
        __syncthreads();
        if (t < 128) {
            unsigned long long mp = 0ULL, mn = ~0ULL;
#pragma unroll
            for (int ww = 0; ww < 4; ++ww) {
                const unsigned long long p = scr[ww * 128 + t];
                const unsigned long long q = scr[512 + ww * 128 + t];
                if (p > mp) mp = p;
                if (q < mn) mn = q;
            }
            atomicMax(&pos_pack[J0 + t], mp);
            atomicMin(&neg_pack[J0 + t], mn);
        }
    }
}

// ---------------------------------------------------------------------------
// Kernel 3: finalize -> int32 outputs [anchor | pos | neg | keep]
// ---------------------------------------------------------------------------
__global__ void finalize_kernel(const unsigned long long* __restrict__ pos_pack,
                                const unsigned long long* __restrict__ neg_pack,
                                const int* __restrict__ labels,
                                const int* __restrict__ hist,
                                int* __restrict__ out) {
    const int r = blockIdx.x * 256 + threadIdx.x;
    out[r]         = r;
    out[N + r]     = 8191 - (int)(pos_pack[r] & 0xFFFFFFFFULL);
    out[2 * N + r] = (int)(neg_pack[r] & 0xFFFFFFFFULL);
    const int cnt = hist[labels[r]];
    out[3 * N + r] = (cnt >= 2 && cnt < N) ? 1 : 0;
}

extern "C" void kernel_launch(void* const* d_in, const int* in_sizes, int n_in,
                              void* d_out, int out_size, void* d_ws, size_t ws_size,
                              hipStream_t stream) {
    const float* x      = (const float*)d_in[0];
    const int*   labels = (const int*)d_in[1];
    int* out = (int*)d_out;

    float* ws  = (float*)d_ws;
    float* xnT = ws;                                        // N*D floats (4 MB)
    float* sq  = xnT + (size_t)N * D;                       // N floats
    unsigned long long* pos_pack =
        (unsigned long long*)(sq + N);                      // N u64
    int* hist = (int*)(pos_pack + N);                       // NC ints (adjacent: one memset)
    unsigned long long* neg_pack =
        (unsigned long long*)(hist + NC);                   // N u64

    hipMemsetAsync(pos_pack, 0x00, N * 8 + NC * 4, stream);     // pos init + hist zero
    hipMemsetAsync(neg_pack, 0xFF, N * 8, stream);              // neg init
    normalize_kernel<<<N / 64, 256, 0, stream>>>(x, labels, xnT, sq, hist);
    miner_kernel<<<NBLK, 256, 0, stream>>>(xnT, sq, labels, pos_pack, neg_pack);
    finalize_kernel<<<N / 256, 256, 0, stream>>>(pos_pack, neg_pack, labels, hist, out);
}